// Round 13
// baseline (582.811 us; speedup 1.0000x reference)
//
#include <hip/hip_runtime.h>
#include <hip/hip_bf16.h>

#define KN 16384
#define KD 1024
#define NB (KN / 128)   // 128 tile-blocks per dimension

typedef __attribute__((ext_vector_type(4))) int   i32x4;
typedef __attribute__((ext_vector_type(8))) int   i32x8;  // 32 fp8 bytes (8 VGPRs)
typedef __attribute__((ext_vector_type(4))) float f32x4;  // MFMA 16x16 accumulator

#define SCALE_ONE 0x7F7F7F7F  // e8m0 1.0 in every byte (opsel-proof)

__device__ __forceinline__ unsigned long long pack_max(float v, int idx) {
  unsigned u = __float_as_uint(v);
  u = (u & 0x80000000u) ? ~u : (u | 0x80000000u);  // order-preserving encode
  return ((unsigned long long)u << 32) | (unsigned)idx;
}

// Fragment DIRECT from global (flatmm): xn is row-major k-contiguous, and the
// 16x16x128 f8f6f4 A/B fragment is exactly 32 contiguous k-bytes per lane
// (row = l15, k = quad*32..+32) -> two global dwordx4 loads, pure SSA value
// (never write a local through a casted pointer — R4-R6 SROA/scratch lesson).
__device__ __forceinline__ i32x8 ldg_frag(const unsigned char* p) {
  const i32x4 lo = *(const i32x4*)p;
  const i32x4 hi = *(const i32x4*)(p + 16);
  return __builtin_shufflevector(lo, hi, 0, 1, 2, 3, 4, 5, 6, 7);
}

// ---------------- row L2-normalize, fp32 -> fp8 e4m3 (+ best[] init) --------
// One WAVE per row (4 rows/block): no LDS, no barrier — pure shfl_xor.
__global__ __launch_bounds__(256) void k_normalize(const float* __restrict__ x,
                                                   unsigned char* __restrict__ xn,
                                                   unsigned long long* __restrict__ best) {
  const int lane = threadIdx.x & 63;
  const int wave = threadIdx.x >> 6;
  const int row  = (blockIdx.x << 2) + wave;
  if (lane == 0) best[row] = 0ull;  // enc(any dot >= -1) > 0, so 0 is identity
  const float4* xr = (const float4*)(x + (size_t)row * KD);
  const float4 v0 = xr[lane];
  const float4 v1 = xr[lane + 64];
  const float4 v2 = xr[lane + 128];
  const float4 v3 = xr[lane + 192];
  float ss = v0.x * v0.x + v0.y * v0.y + v0.z * v0.z + v0.w * v0.w
           + v1.x * v1.x + v1.y * v1.y + v1.z * v1.z + v1.w * v1.w
           + v2.x * v2.x + v2.y * v2.y + v2.z * v2.z + v2.w * v2.w
           + v3.x * v3.x + v3.y * v3.y + v3.z * v3.z + v3.w * v3.w;
#pragma unroll
  for (int off = 32; off > 0; off >>= 1) ss += __shfl_xor(ss, off);
  const float scale = 1.0f / fmaxf(sqrtf(ss), 1e-8f);  // F.normalize eps=1e-8
  int4 o;
  int pk = __builtin_amdgcn_cvt_pk_fp8_f32(v0.x * scale, v0.y * scale, 0, false);
  o.x = __builtin_amdgcn_cvt_pk_fp8_f32(v0.z * scale, v0.w * scale, pk, true);
  pk  = __builtin_amdgcn_cvt_pk_fp8_f32(v1.x * scale, v1.y * scale, 0, false);
  o.y = __builtin_amdgcn_cvt_pk_fp8_f32(v1.z * scale, v1.w * scale, pk, true);
  pk  = __builtin_amdgcn_cvt_pk_fp8_f32(v2.x * scale, v2.y * scale, 0, false);
  o.z = __builtin_amdgcn_cvt_pk_fp8_f32(v2.z * scale, v2.w * scale, pk, true);
  pk  = __builtin_amdgcn_cvt_pk_fp8_f32(v3.x * scale, v3.y * scale, 0, false);
  o.w = __builtin_amdgcn_cvt_pk_fp8_f32(v3.z * scale, v3.w * scale, pk, true);
  int* or_ = (int*)(xn + (size_t)row * KD);
  or_[lane]       = o.x;   // k-order preserved: each int = 4 consecutive fp8
  or_[lane + 64]  = o.y;
  or_[lane + 128] = o.z;
  or_[lane + 192] = o.w;
}

// ---------------- fused symmetric NT-GEMM (fp8, MX-scaled) + two-sided argmax
// FLATMM K-loop: fragments loaded directly global->VGPR (no LDS, no
// __syncthreads, no swizzle). R12's LDS-staged loop was pipe-serialized:
// MFMA 27% + VALU 33% + LDS-read ~38% ~= 100%. Here the LDS phase and both
// barriers vanish; waves free-run and the compiler's vmcnt scheduling
// overlaps loads with MFMA. Fragment bytes are read 2x per block (two waves
// share each row) but come from per-XCD L2 (supertiled cover, working set
// ~3 MB < 4 MB). K-loop VALU ~ 0: 8 base pointers + offset immediates.
// Circulant cover bx = by + d mod NB; 8x8 (by,d) chunks round-robin over
// XCDs via id&7.
__global__ __launch_bounds__(256, 2) void k_nn_argmax(const unsigned char* __restrict__ xn,
                                                      unsigned long long* __restrict__ best) {
  const int id = blockIdx.x;
  int d, by;
  if (id < 8192) {                      // main region: d in [0,64)
    const int o   = id & 7;             // XCD (round-robin heuristic)
    const int idp = id >> 3;            // per-XCD sequence
    const int k   = idp >> 6;           // chunk counter (0..15)
    const int p   = idp & 63;           // position within 8x8 chunk
    const int q   = o + (k << 3);       // global chunk id (0..127)
    by = ((q & 15) << 3) + (p & 7);     // by-chunk * 8 + row-in-chunk
    d  = ((q >> 4) << 3) + (p >> 3);    // d-chunk * 8 + d-in-chunk
  } else {                              // tail: d == 64, by in [0,64)
    d  = NB / 2;
    by = id - 8192;
  }
  const int bx = (by + d) & (NB - 1);   // col tile

  const int tid  = threadIdx.x;
  const int lane = tid & 63;
  const int wave = tid >> 6;
  const int wm   = wave >> 1;           // wave row (0..1)
  const int wn   = wave & 1;            // wave col (0..1)
  const int quad = lane >> 4;
  const int l15  = lane & 15;

  f32x4 acc[4][4];
#pragma unroll
  for (int i = 0; i < 4; i++)
#pragma unroll
    for (int j = 0; j < 4; j++) acc[i][j] = (f32x4){0.f, 0.f, 0.f, 0.f};

  // 8 per-lane fragment base pointers (k0 folds into the 13-bit inst offset)
  const unsigned char* pa0 = xn + (size_t)((by << 7) + wm * 64 +  0 + l15) * KD + (quad << 5);
  const unsigned char* pa1 = pa0 + 16 * KD;
  const unsigned char* pa2 = pa0 + 32 * KD;
  const unsigned char* pa3 = pa0 + 48 * KD;
  const unsigned char* pb0 = xn + (size_t)((bx << 7) + wn * 64 +  0 + l15) * KD + (quad << 5);
  const unsigned char* pb1 = pb0 + 16 * KD;
  const unsigned char* pb2 = pb0 + 32 * KD;
  const unsigned char* pb3 = pb0 + 48 * KD;

#pragma unroll 2
  for (int k0 = 0; k0 < KD; k0 += 128) {
    const i32x8 a0 = ldg_frag(pa0 + k0);
    const i32x8 a1 = ldg_frag(pa1 + k0);
    const i32x8 a2 = ldg_frag(pa2 + k0);
    const i32x8 a3 = ldg_frag(pa3 + k0);
    const i32x8 b0 = ldg_frag(pb0 + k0);
    const i32x8 b1 = ldg_frag(pb1 + k0);
    const i32x8 b2 = ldg_frag(pb2 + k0);
    const i32x8 b3 = ldg_frag(pb3 + k0);
    acc[0][0] = __builtin_amdgcn_mfma_scale_f32_16x16x128_f8f6f4(a0, b0, acc[0][0], 0, 0, 0, SCALE_ONE, 0, SCALE_ONE);
    acc[1][0] = __builtin_amdgcn_mfma_scale_f32_16x16x128_f8f6f4(a1, b0, acc[1][0], 0, 0, 0, SCALE_ONE, 0, SCALE_ONE);
    acc[2][0] = __builtin_amdgcn_mfma_scale_f32_16x16x128_f8f6f4(a2, b0, acc[2][0], 0, 0, 0, SCALE_ONE, 0, SCALE_ONE);
    acc[3][0] = __builtin_amdgcn_mfma_scale_f32_16x16x128_f8f6f4(a3, b0, acc[3][0], 0, 0, 0, SCALE_ONE, 0, SCALE_ONE);
    acc[0][1] = __builtin_amdgcn_mfma_scale_f32_16x16x128_f8f6f4(a0, b1, acc[0][1], 0, 0, 0, SCALE_ONE, 0, SCALE_ONE);
    acc[1][1] = __builtin_amdgcn_mfma_scale_f32_16x16x128_f8f6f4(a1, b1, acc[1][1], 0, 0, 0, SCALE_ONE, 0, SCALE_ONE);
    acc[2][1] = __builtin_amdgcn_mfma_scale_f32_16x16x128_f8f6f4(a2, b1, acc[2][1], 0, 0, 0, SCALE_ONE, 0, SCALE_ONE);
    acc[3][1] = __builtin_amdgcn_mfma_scale_f32_16x16x128_f8f6f4(a3, b1, acc[3][1], 0, 0, 0, SCALE_ONE, 0, SCALE_ONE);
    acc[0][2] = __builtin_amdgcn_mfma_scale_f32_16x16x128_f8f6f4(a0, b2, acc[0][2], 0, 0, 0, SCALE_ONE, 0, SCALE_ONE);
    acc[1][2] = __builtin_amdgcn_mfma_scale_f32_16x16x128_f8f6f4(a1, b2, acc[1][2], 0, 0, 0, SCALE_ONE, 0, SCALE_ONE);
    acc[2][2] = __builtin_amdgcn_mfma_scale_f32_16x16x128_f8f6f4(a2, b2, acc[2][2], 0, 0, 0, SCALE_ONE, 0, SCALE_ONE);
    acc[3][2] = __builtin_amdgcn_mfma_scale_f32_16x16x128_f8f6f4(a3, b2, acc[3][2], 0, 0, 0, SCALE_ONE, 0, SCALE_ONE);
    acc[0][3] = __builtin_amdgcn_mfma_scale_f32_16x16x128_f8f6f4(a0, b3, acc[0][3], 0, 0, 0, SCALE_ONE, 0, SCALE_ONE);
    acc[1][3] = __builtin_amdgcn_mfma_scale_f32_16x16x128_f8f6f4(a1, b3, acc[1][3], 0, 0, 0, SCALE_ONE, 0, SCALE_ONE);
    acc[2][3] = __builtin_amdgcn_mfma_scale_f32_16x16x128_f8f6f4(a2, b3, acc[2][3], 0, 0, 0, SCALE_ONE, 0, SCALE_ONE);
    acc[3][3] = __builtin_amdgcn_mfma_scale_f32_16x16x128_f8f6f4(a3, b3, acc[3][3], 0, 0, 0, SCALE_ONE, 0, SCALE_ONE);
  }

  // ---- Epilogue pass 1: row argmax (C/D layout: col = lane&15, row = quad*4+reg)
#pragma unroll
  for (int i = 0; i < 4; i++) {
#pragma unroll
    for (int r = 0; r < 4; r++) {
      const int grow = (by << 7) + wm * 64 + i * 16 + quad * 4 + r;
      float v = -3.0f;
      int   c = 0;
#pragma unroll
      for (int j = 0; j < 4; j++) {
        const int gcol = (bx << 7) + wn * 64 + j * 16 + l15;
        float val = acc[i][j][r];
        if (gcol == grow) val = -3.0f;  // mask self-similarity
        if (val > v) { v = val; c = gcol; }
      }
#pragma unroll
      for (int off = 1; off < 16; off <<= 1) {
        const float ov = __shfl_xor(v, off);
        const int   oc = __shfl_xor(c, off);
        if (ov > v) { v = ov; c = oc; }
      }
      if (l15 == 0) atomicMax(best + grow, pack_max(v, c));
    }
  }

  // ---- Epilogue pass 2: col argmax via symmetry (off-diagonal blocks only)
  if (d != 0) {
#pragma unroll
    for (int j = 0; j < 4; j++) {
      const int gcol = (bx << 7) + wn * 64 + j * 16 + l15;
      float v = -3.0f;
      int   rb = 0;
#pragma unroll
      for (int i = 0; i < 4; i++) {
#pragma unroll
        for (int r = 0; r < 4; r++) {
          const int grow = (by << 7) + wm * 64 + i * 16 + quad * 4 + r;
          float val = acc[i][j][r];
          if (gcol == grow) val = -3.0f;
          if (val > v) { v = val; rb = grow; }
        }
      }
      // reduce across the 4 quads (lanes sharing l15 hold the same column)
#pragma unroll
      for (int off = 16; off < 64; off <<= 1) {
        const float ov = __shfl_xor(v, off);
        const int   orr = __shfl_xor(rb, off);
        if (ov > v) { v = ov; rb = orr; }
      }
      if (quad == 0) atomicMax(best + gcol, pack_max(v, rb));
    }
  }
}

// ---------------- distance to NN + -log (wave per row, plain store) ---------
__global__ __launch_bounds__(256) void k_dist(const float* __restrict__ x,
                                              const unsigned long long* __restrict__ best,
                                              float* __restrict__ rowlog) {
  const int lane = threadIdx.x & 63;
  const int wave = threadIdx.x >> 6;
  const int row  = (blockIdx.x << 2) + wave;
  const int nb   = (int)(best[row] & 0xffffffffu);
  const float4* ar = (const float4*)(x + (size_t)row * KD);
  const float4* br = (const float4*)(x + (size_t)nb * KD);
  float ss = 0.f;
#pragma unroll
  for (int q = 0; q < 4; q++) {
    const float4 a = ar[lane + 64 * q];
    const float4 b = br[lane + 64 * q];
    const float dx = a.x - b.x + 1e-6f;  // torch PairwiseDistance eps on the diff
    const float dy = a.y - b.y + 1e-6f;
    const float dz = a.z - b.z + 1e-6f;
    const float dw = a.w - b.w + 1e-6f;
    ss += dx * dx + dy * dy + dz * dz + dw * dw;
  }
#pragma unroll
  for (int off = 32; off > 0; off >>= 1) ss += __shfl_xor(ss, off);
  if (lane == 0) rowlog[row] = -logf(sqrtf(ss));
}

// ---------------- final mean (1024 threads, 16 waves) ----------------
__global__ __launch_bounds__(1024) void k_final(const float* __restrict__ rowlog,
                                                float* __restrict__ out) {
  const int tid = threadIdx.x;
  float s = 0.f;
  for (int i = tid; i < KN; i += 1024) s += rowlog[i];
#pragma unroll
  for (int off = 32; off > 0; off >>= 1) s += __shfl_down(s, off);
  __shared__ float ws[16];
  if ((tid & 63) == 0) ws[tid >> 6] = s;
  __syncthreads();
  if (tid == 0) {
    float t = 0.f;
#pragma unroll
    for (int i = 0; i < 16; i++) t += ws[i];
    out[0] = t / (float)KN;
  }
}

extern "C" void kernel_launch(void* const* d_in, const int* in_sizes, int n_in,
                              void* d_out, int out_size, void* d_ws, size_t ws_size,
                              hipStream_t stream) {
  const float* x = (const float*)d_in[0];
  float* out = (float*)d_out;

  char* ws = (char*)d_ws;
  unsigned char* xn = (unsigned char*)ws;                                     // 16 MB fp8
  unsigned long long* best = (unsigned long long*)(ws + (size_t)KN * KD);     // 128 KB
  float* rowlog = (float*)(ws + (size_t)KN * KD + (size_t)KN * 8);            // 64 KB

  k_normalize<<<KN / 4, 256, 0, stream>>>(x, xn, best);
  k_nn_argmax<<<8192 + 64, 256, 0, stream>>>(xn, best);  // supertiled 1D cover
  k_dist<<<KN / 4, 256, 0, stream>>>(x, best, rowlog);
  k_final<<<1, 1024, 0, stream>>>(rowlog, out);
}

// Round 14
// 301.563 us; speedup vs baseline: 1.9326x; 1.9326x over previous
//
#include <hip/hip_runtime.h>
#include <hip/hip_bf16.h>

#define KN 16384
#define KD 1024
#define NB (KN / 128)   // 128 tile-blocks per dimension

typedef __attribute__((ext_vector_type(4))) int   i32x4;
typedef __attribute__((ext_vector_type(8))) int   i32x8;  // 32 fp8 bytes (8 VGPRs)
typedef __attribute__((ext_vector_type(4))) float f32x4;  // MFMA 16x16 accumulator

#define SCALE_ONE 0x7F7F7F7F  // e8m0 1.0 in every byte (opsel-proof)

// Build an i32x8 fragment as a pure SSA value: two direct LDS vector loads +
// shufflevector. NEVER write into a local through a casted pointer — that
// defeats SROA and puts the fragment in scratch (R4-R6: 2-2.7 GB/dispatch of
// alloca traffic, MfmaUtil 4-6%). Row stride 128 B (R7 layout).
// NOTE (R13): do NOT load fragments direct from global — the 16-rows-per-
// instruction stride pattern is TA-transaction-bound (496 µs, MfmaUtil 11%).
#define LOAD_FRAG(dst, basePtr, r)                                        \
  {                                                                       \
    const i32x4 lo_ = *(const i32x4*)&(basePtr)[(r) * 128 + p0];          \
    const i32x4 hi_ = *(const i32x4*)&(basePtr)[(r) * 128 + p1];          \
    dst = __builtin_shufflevector(lo_, hi_, 0, 1, 2, 3, 4, 5, 6, 7);      \
  }

__device__ __forceinline__ void load_lds16(const void* g, void* l) {
  // async global->LDS, 16B/lane; LDS dest is wave-uniform base + lane*16
  __builtin_amdgcn_global_load_lds(
      (const __attribute__((address_space(1))) unsigned int*)g,
      (__attribute__((address_space(3))) unsigned int*)l, 16, 0, 0);
}

__device__ __forceinline__ unsigned long long pack_max(float v, int idx) {
  unsigned u = __float_as_uint(v);
  u = (u & 0x80000000u) ? ~u : (u | 0x80000000u);  // order-preserving encode
  return ((unsigned long long)u << 32) | (unsigned)idx;
}

// ---------------- row L2-normalize, fp32 -> fp8 e4m3 (+ best[] init) --------
// One WAVE per row (4 rows/block): no LDS, no barrier — pure shfl_xor.
__global__ __launch_bounds__(256) void k_normalize(const float* __restrict__ x,
                                                   unsigned char* __restrict__ xn,
                                                   unsigned long long* __restrict__ best) {
  const int lane = threadIdx.x & 63;
  const int wave = threadIdx.x >> 6;
  const int row  = (blockIdx.x << 2) + wave;
  if (lane == 0) best[row] = 0ull;  // enc(any dot >= -1) > 0, so 0 is identity
  const float4* xr = (const float4*)(x + (size_t)row * KD);
  const float4 v0 = xr[lane];
  const float4 v1 = xr[lane + 64];
  const float4 v2 = xr[lane + 128];
  const float4 v3 = xr[lane + 192];
  float ss = v0.x * v0.x + v0.y * v0.y + v0.z * v0.z + v0.w * v0.w
           + v1.x * v1.x + v1.y * v1.y + v1.z * v1.z + v1.w * v1.w
           + v2.x * v2.x + v2.y * v2.y + v2.z * v2.z + v2.w * v2.w
           + v3.x * v3.x + v3.y * v3.y + v3.z * v3.z + v3.w * v3.w;
#pragma unroll
  for (int off = 32; off > 0; off >>= 1) ss += __shfl_xor(ss, off);
  const float scale = 1.0f / fmaxf(sqrtf(ss), 1e-8f);  // F.normalize eps=1e-8
  int4 o;
  int pk = __builtin_amdgcn_cvt_pk_fp8_f32(v0.x * scale, v0.y * scale, 0, false);
  o.x = __builtin_amdgcn_cvt_pk_fp8_f32(v0.z * scale, v0.w * scale, pk, true);
  pk  = __builtin_amdgcn_cvt_pk_fp8_f32(v1.x * scale, v1.y * scale, 0, false);
  o.y = __builtin_amdgcn_cvt_pk_fp8_f32(v1.z * scale, v1.w * scale, pk, true);
  pk  = __builtin_amdgcn_cvt_pk_fp8_f32(v2.x * scale, v2.y * scale, 0, false);
  o.z = __builtin_amdgcn_cvt_pk_fp8_f32(v2.z * scale, v2.w * scale, pk, true);
  pk  = __builtin_amdgcn_cvt_pk_fp8_f32(v3.x * scale, v3.y * scale, 0, false);
  o.w = __builtin_amdgcn_cvt_pk_fp8_f32(v3.z * scale, v3.w * scale, pk, true);
  int* or_ = (int*)(xn + (size_t)row * KD);
  or_[lane]       = o.x;   // k-order preserved: each int = 4 consecutive fp8
  or_[lane + 64]  = o.y;
  or_[lane + 128] = o.z;
  or_[lane + 192] = o.w;
}

// ---------------- fused symmetric NT-GEMM (fp8, MX-scaled) + two-sided argmax
// R12 kernel verbatim (best measured: 215 µs GEMM / 303 µs total). BK=128,
// 32 KB LDS, VGPR 84 + 64 acc. Circulant cover bx = by + d mod NB; 8x8
// (by,d) chunks round-robin over XCDs via id&7 -> working set ~3 MB < 4 MB
// per-XCD L2. Remaining gap to the MX ceiling is the m97-family structural
// plateau (LDS-read / MFMA / VALU phases near-serialized around the
// barrier); R8 (BK=256) and R13 (flatmm) restructures both regressed.
__global__ __launch_bounds__(256, 2) void k_nn_argmax(const unsigned char* __restrict__ xn,
                                                      unsigned long long* __restrict__ best) {
  const int id = blockIdx.x;
  int d, by;
  if (id < 8192) {                      // main region: d in [0,64)
    const int o   = id & 7;             // XCD (round-robin heuristic)
    const int idp = id >> 3;            // per-XCD sequence
    const int k   = idp >> 6;           // chunk counter (0..15)
    const int p   = idp & 63;           // position within 8x8 chunk
    const int q   = o + (k << 3);       // global chunk id (0..127)
    by = ((q & 15) << 3) + (p & 7);     // by-chunk * 8 + row-in-chunk
    d  = ((q >> 4) << 3) + (p >> 3);    // d-chunk * 8 + d-in-chunk
  } else {                              // tail: d == 64, by in [0,64)
    d  = NB / 2;
    by = id - 8192;
  }
  const int bx = (by + d) & (NB - 1);   // col tile

  __shared__ __align__(16) unsigned char As[128 * 128];
  __shared__ __align__(16) unsigned char Bs[128 * 128];
  const int tid  = threadIdx.x;
  const int lane = tid & 63;
  const int wave = tid >> 6;
  const int wm   = wave >> 1;           // wave row (0..1)
  const int wn   = wave & 1;            // wave col (0..1)
  const int quad = lane >> 4;
  const int l15  = lane & 15;

  f32x4 acc[4][4];
#pragma unroll
  for (int i = 0; i < 4; i++)
#pragma unroll
    for (int j = 0; j < 4; j++) acc[i][j] = (f32x4){0.f, 0.f, 0.f, 0.f};

  // staging: lane handles (row = tid>>3 within 32-row line, chunk (tid&7)^swz)
  const int lrow = tid >> 3;                              // 0..31
  const int swz  = ((tid & 7) ^ (lrow & 7)) << 4;         // swizzled 16B chunk
  const unsigned char* ga = xn + (size_t)((by << 7) + lrow) * KD + swz;
  const unsigned char* gb = xn + (size_t)((bx << 7) + lrow) * KD + swz;

  // fragment chunk positions (16B-chunk XOR swizzle: pos = chunk ^ (row&7))
  const int p0 = ((quad << 1) ^ (l15 & 7)) << 4;          // k = quad*32..+15
  const int p1 = p0 ^ 16;                                 // k = quad*32+16..+31

  for (int k0 = 0; k0 < KD; k0 += 128) {
#pragma unroll
    for (int L = 0; L < 4; L++) {       // 4 lines x 32 rows = 128 rows
      load_lds16(ga + (size_t)L * 32 * KD + k0, &As[L * 4096 + tid * 16]);
      load_lds16(gb + (size_t)L * 32 * KD + k0, &Bs[L * 4096 + tid * 16]);
    }
    __syncthreads();  // drains vmcnt before LDS reads

    i32x8 a0, a1, a2, a3;
    LOAD_FRAG(a0, As, wm * 64 +  0 + l15);
    LOAD_FRAG(a1, As, wm * 64 + 16 + l15);
    LOAD_FRAG(a2, As, wm * 64 + 32 + l15);
    LOAD_FRAG(a3, As, wm * 64 + 48 + l15);
#pragma unroll
    for (int j = 0; j < 4; j++) {
      i32x8 b;
      LOAD_FRAG(b, Bs, wn * 64 + j * 16 + l15);
      acc[0][j] = __builtin_amdgcn_mfma_scale_f32_16x16x128_f8f6f4(
          a0, b, acc[0][j], 0, 0, 0, SCALE_ONE, 0, SCALE_ONE);
      acc[1][j] = __builtin_amdgcn_mfma_scale_f32_16x16x128_f8f6f4(
          a1, b, acc[1][j], 0, 0, 0, SCALE_ONE, 0, SCALE_ONE);
      acc[2][j] = __builtin_amdgcn_mfma_scale_f32_16x16x128_f8f6f4(
          a2, b, acc[2][j], 0, 0, 0, SCALE_ONE, 0, SCALE_ONE);
      acc[3][j] = __builtin_amdgcn_mfma_scale_f32_16x16x128_f8f6f4(
          a3, b, acc[3][j], 0, 0, 0, SCALE_ONE, 0, SCALE_ONE);
    }
    __syncthreads();
  }

  // ---- Epilogue pass 1: row argmax (C/D layout: col = lane&15, row = quad*4+reg)
#pragma unroll
  for (int i = 0; i < 4; i++) {
#pragma unroll
    for (int r = 0; r < 4; r++) {
      const int grow = (by << 7) + wm * 64 + i * 16 + quad * 4 + r;
      float v = -3.0f;
      int   c = 0;
#pragma unroll
      for (int j = 0; j < 4; j++) {
        const int gcol = (bx << 7) + wn * 64 + j * 16 + l15;
        float val = acc[i][j][r];
        if (gcol == grow) val = -3.0f;  // mask self-similarity
        if (val > v) { v = val; c = gcol; }
      }
#pragma unroll
      for (int off = 1; off < 16; off <<= 1) {
        const float ov = __shfl_xor(v, off);
        const int   oc = __shfl_xor(c, off);
        if (ov > v) { v = ov; c = oc; }
      }
      if (l15 == 0) atomicMax(best + grow, pack_max(v, c));
    }
  }

  // ---- Epilogue pass 2: col argmax via symmetry (off-diagonal blocks only)
  if (d != 0) {
#pragma unroll
    for (int j = 0; j < 4; j++) {
      const int gcol = (bx << 7) + wn * 64 + j * 16 + l15;
      float v = -3.0f;
      int   rb = 0;
#pragma unroll
      for (int i = 0; i < 4; i++) {
#pragma unroll
        for (int r = 0; r < 4; r++) {
          const int grow = (by << 7) + wm * 64 + i * 16 + quad * 4 + r;
          float val = acc[i][j][r];
          if (gcol == grow) val = -3.0f;
          if (val > v) { v = val; rb = grow; }
        }
      }
      // reduce across the 4 quads (lanes sharing l15 hold the same column)
#pragma unroll
      for (int off = 16; off < 64; off <<= 1) {
        const float ov = __shfl_xor(v, off);
        const int   orr = __shfl_xor(rb, off);
        if (ov > v) { v = ov; rb = orr; }
      }
      if (quad == 0) atomicMax(best + gcol, pack_max(v, rb));
    }
  }
}

// ---------------- distance to NN + -log (wave per row, plain store) ---------
__global__ __launch_bounds__(256) void k_dist(const float* __restrict__ x,
                                              const unsigned long long* __restrict__ best,
                                              float* __restrict__ rowlog) {
  const int lane = threadIdx.x & 63;
  const int wave = threadIdx.x >> 6;
  const int row  = (blockIdx.x << 2) + wave;
  const int nb   = (int)(best[row] & 0xffffffffu);
  const float4* ar = (const float4*)(x + (size_t)row * KD);
  const float4* br = (const float4*)(x + (size_t)nb * KD);
  float ss = 0.f;
#pragma unroll
  for (int q = 0; q < 4; q++) {
    const float4 a = ar[lane + 64 * q];
    const float4 b = br[lane + 64 * q];
    const float dx = a.x - b.x + 1e-6f;  // torch PairwiseDistance eps on the diff
    const float dy = a.y - b.y + 1e-6f;
    const float dz = a.z - b.z + 1e-6f;
    const float dw = a.w - b.w + 1e-6f;
    ss += dx * dx + dy * dy + dz * dz + dw * dw;
  }
#pragma unroll
  for (int off = 32; off > 0; off >>= 1) ss += __shfl_xor(ss, off);
  if (lane == 0) rowlog[row] = -logf(sqrtf(ss));
}

// ---------------- final mean (1024 threads, 16 waves) ----------------
__global__ __launch_bounds__(1024) void k_final(const float* __restrict__ rowlog,
                                                float* __restrict__ out) {
  const int tid = threadIdx.x;
  float s = 0.f;
  for (int i = tid; i < KN; i += 1024) s += rowlog[i];
#pragma unroll
  for (int off = 32; off > 0; off >>= 1) s += __shfl_down(s, off);
  __shared__ float ws[16];
  if ((tid & 63) == 0) ws[tid >> 6] = s;
  __syncthreads();
  if (tid == 0) {
    float t = 0.f;
#pragma unroll
    for (int i = 0; i < 16; i++) t += ws[i];
    out[0] = t / (float)KN;
  }
}

extern "C" void kernel_launch(void* const* d_in, const int* in_sizes, int n_in,
                              void* d_out, int out_size, void* d_ws, size_t ws_size,
                              hipStream_t stream) {
  const float* x = (const float*)d_in[0];
  float* out = (float*)d_out;

  char* ws = (char*)d_ws;
  unsigned char* xn = (unsigned char*)ws;                                     // 16 MB fp8
  unsigned long long* best = (unsigned long long*)(ws + (size_t)KN * KD);     // 128 KB
  float* rowlog = (float*)(ws + (size_t)KN * KD + (size_t)KN * 8);            // 64 KB

  k_normalize<<<KN / 4, 256, 0, stream>>>(x, xn, best);
  k_nn_argmax<<<8192 + 64, 256, 0, stream>>>(xn, best);  // supertiled 1D cover
  k_dist<<<KN / 4, 256, 0, stream>>>(x, best, rowlog);
  k_final<<<1, 1024, 0, stream>>>(rowlog, out);
}